// Round 18
// baseline (594.729 us; speedup 1.0000x reference)
//
#include <hip/hip_runtime.h>

// Sizes (fixed by the reference)
#define DIN 32
#define HDIM 64
#define DOUT 8
#define NGRAPH 64
#define EDIM 15
#define SCAN_BS 512

__device__ __forceinline__ int clampidx(int v, int n) {
    return ((unsigned)v < (unsigned)n) ? v : 0;
}

// bf16 helpers (round-to-nearest-even store, cheap decode)
__device__ __forceinline__ unsigned short f2b(float f) {
    unsigned int u = __float_as_uint(f);
    u = (u + 0x7FFF + ((u >> 16) & 1)) >> 16;
    return (unsigned short)u;
}
__device__ __forceinline__ float b2f(unsigned short b) {
    return __uint_as_float(((unsigned int)b) << 16);
}

// monotonic float<->uint encoding for atomicMax
__device__ __forceinline__ unsigned int fkey(float f) {
    unsigned int b = __float_as_uint(f);
    return (b & 0x80000000u) ? ~b : (b | 0x80000000u);
}
__device__ __forceinline__ float funkey(unsigned int k) {
    unsigned int b = (k & 0x80000000u) ? (k ^ 0x80000000u) : ~k;
    return __uint_as_float(b);
}

// ---------------- encoder: h0 = relu(x @ enc_W + enc_b) -> bf16; block = 4 nodes ----------------
__global__ __launch_bounds__(256) void k_enc_b(const float* __restrict__ x,
                                               const float* __restrict__ W,
                                               const float* __restrict__ b,
                                               unsigned short* __restrict__ h, int n_nodes) {
    __shared__ float xs[4][DIN];
    const int j = threadIdx.x & 63;
    const int q = threadIdx.x >> 6;
    const int n = blockIdx.x * 4 + q;
    const bool ok = (n < n_nodes);
    if (ok && j < DIN) xs[q][j] = x[(size_t)n * DIN + j];
    __syncthreads();
    if (ok) {
        float acc = b[j];
#pragma unroll
        for (int k = 0; k < DIN; ++k) acc = fmaf(xs[q][k], W[k * HDIM + j], acc);
        h[(size_t)n * HDIM + j] = f2b(fmaxf(acc, 0.f));
    }
}

// ---------------- degree+rank + eattr->bf16 convert (edge-order), thread per edge ----------------
__global__ __launch_bounds__(256) void k_degc(const int* __restrict__ ei,
                                              const float* __restrict__ eattr,
                                              int* __restrict__ degi,
                                              int* __restrict__ rank,
                                              unsigned short* __restrict__ eb,
                                              int E, int n_nodes) {
    int e = blockIdx.x * blockDim.x + threadIdx.x;
    const int stride = gridDim.x * blockDim.x;
    for (; e < E; e += stride) {
        rank[e] = atomicAdd(&degi[clampidx(ei[E + e], n_nodes)], 1);
        // convert row e: 15 fp32 -> 16 bf16 (pad), packed as two uint4 stores
        unsigned short v[16];
#pragma unroll
        for (int d = 0; d < EDIM; ++d) v[d] = f2b(eattr[(size_t)e * EDIM + d]);
        v[15] = 0;
        uint4 lo, hi;
        lo.x = v[0]  | ((unsigned)v[1]  << 16);
        lo.y = v[2]  | ((unsigned)v[3]  << 16);
        lo.z = v[4]  | ((unsigned)v[5]  << 16);
        lo.w = v[6]  | ((unsigned)v[7]  << 16);
        hi.x = v[8]  | ((unsigned)v[9]  << 16);
        hi.y = v[10] | ((unsigned)v[11] << 16);
        hi.z = v[12] | ((unsigned)v[13] << 16);
        hi.w = v[14] | ((unsigned)v[15] << 16);
        uint4* dstp = (uint4*)&eb[(size_t)e * 16];
        dstp[0] = lo;
        dstp[1] = hi;
    }
}

// ---------------- CSR scan stage 1: per-block sum of degrees ----------------
__global__ __launch_bounds__(SCAN_BS) void k_blocksum(const int* __restrict__ degi,
                                                      int* __restrict__ bsum, int n) {
    __shared__ int red[SCAN_BS];
    const int t = threadIdx.x;
    const int i = blockIdx.x * SCAN_BS + t;
    red[t] = (i < n) ? degi[i] : 0;
    __syncthreads();
    for (int off = SCAN_BS / 2; off >= 1; off >>= 1) {
        if (t < off) red[t] += red[t + off];
        __syncthreads();
    }
    if (t == 0) bsum[blockIdx.x] = red[0];
}

// ---------------- CSR scan stage 2: single-thread exclusive scan of block sums ----------------
__global__ __launch_bounds__(64) void k_bscan(const int* __restrict__ bsum,
                                              int* __restrict__ boff,
                                              int* __restrict__ offsets,
                                              int nblk, int n, int E) {
    if (blockIdx.x == 0 && threadIdx.x == 0) {
        int run = 0;
        for (int b = 0; b < nblk; ++b) { boff[b] = run; run += bsum[b]; }
        offsets[n] = E;
    }
}

// ---------------- CSR scan stage 3: per-block single-thread offset emit ----------------
__global__ __launch_bounds__(64) void k_fillofs(const int* __restrict__ degi,
                                                const int* __restrict__ boff,
                                                int* __restrict__ offsets, int n) {
    if (threadIdx.x != 0) return;
    const int b = blockIdx.x;
    int run = boff[b];
    const int i0 = b * SCAN_BS;
    const int i1 = (i0 + SCAN_BS < n) ? i0 + SCAN_BS : n;
    for (int i = i0; i < i1; ++i) {
        offsets[i] = run;
        run += degi[i];
    }
}

// ---------------- CSR fill (atomic-free): pe[offsets[dst]+rank[e]] <- (src, e) ----------------
__global__ __launch_bounds__(256) void k_fill(const int* __restrict__ ei,
                                              const int* __restrict__ offsets,
                                              const int* __restrict__ rank,
                                              int2* __restrict__ pe, int E, int n_nodes) {
    int e = blockIdx.x * blockDim.x + threadIdx.x;
    if (e >= E) return;
    int dst = clampidx(ei[E + e], n_nodes);
    int pos = offsets[dst] + rank[e];
    if ((unsigned)pos < (unsigned)E) pe[pos] = make_int2(clampidx(ei[e], n_nodes), e);
}

// ---------------- layer 0 fused: gather(h bf16) + gather(eb bf16) + transform -> hb1, ea ----------------
__global__ __launch_bounds__(256) void k_gxf0(const unsigned short* __restrict__ hprev,
                                              const unsigned short* __restrict__ eb,
                                              const int* __restrict__ degi,
                                              const int* __restrict__ offsets,
                                              const int2* __restrict__ pe,
                                              const float* __restrict__ linW,
                                              const float* __restrict__ linb,
                                              const float* __restrict__ edgeW,
                                              const float* __restrict__ edgeb,
                                              unsigned short* __restrict__ hnext,
                                              float* __restrict__ ea_out,
                                              int n_nodes, int E) {
    __shared__ float As[4][HDIM];
    __shared__ float es[4][EDIM];
    const int j = threadIdx.x & 63;
    const int q = threadIdx.x >> 6;
    const bool ed = (j < EDIM);
    int w  = (blockIdx.x * blockDim.x + threadIdx.x) >> 6;
    const int nw = (gridDim.x * blockDim.x) >> 6;
    for (int n = w; n < n_nodes; n += nw) {
        int rs = offsets[n], re = offsets[n + 1];
        if (rs < 0) rs = 0;
        if (re > E) re = E;
        if (re < rs) re = rs;
        float A0 = 0.f, A1 = 0.f, A2 = 0.f, A3 = 0.f;
        float e0 = 0.f, e1 = 0.f, e2 = 0.f, e3 = 0.f;
        int jj = rs;
        for (; jj + 4 <= re; jj += 4) {
            int2 p0 = pe[jj], p1 = pe[jj + 1], p2 = pe[jj + 2], p3 = pe[jj + 3];
            int s0 = clampidx(p0.x, n_nodes), s1 = clampidx(p1.x, n_nodes);
            int s2 = clampidx(p2.x, n_nodes), s3 = clampidx(p3.x, n_nodes);
            A0 += b2f(hprev[(size_t)s0 * HDIM + j]);
            A1 += b2f(hprev[(size_t)s1 * HDIM + j]);
            A2 += b2f(hprev[(size_t)s2 * HDIM + j]);
            A3 += b2f(hprev[(size_t)s3 * HDIM + j]);
            if (ed) {
                e0 += b2f(eb[(size_t)clampidx(p0.y, E) * 16 + j]);
                e1 += b2f(eb[(size_t)clampidx(p1.y, E) * 16 + j]);
                e2 += b2f(eb[(size_t)clampidx(p2.y, E) * 16 + j]);
                e3 += b2f(eb[(size_t)clampidx(p3.y, E) * 16 + j]);
            }
        }
        for (; jj < re; ++jj) {
            int2 p = pe[jj];
            A0 += b2f(hprev[(size_t)clampidx(p.x, n_nodes) * HDIM + j]);
            if (ed) e0 += b2f(eb[(size_t)clampidx(p.y, E) * 16 + j]);
        }
        As[q][j] = (A0 + A1) + (A2 + A3);
        float eacc = (e0 + e1) + (e2 + e3);
        if (ed) {
            es[q][j] = eacc;
            ea_out[(size_t)n * 16 + j] = eacc;
        }
        __builtin_amdgcn_wave_barrier();   // same-wave LDS write->read ordering
        float acc = (linb[j] + edgeb[j]) * (float)degi[n];
#pragma unroll
        for (int k = 0; k < HDIM; ++k) acc = fmaf(As[q][k], linW[k * HDIM + j], acc);
#pragma unroll
        for (int k = 0; k < EDIM; ++k) acc = fmaf(es[q][k], edgeW[k * HDIM + j], acc);
        hnext[(size_t)n * HDIM + j] = f2b(fmaxf(acc, 0.f));
    }
}

// ---------------- layer 1: gather(h bf16) + transform (ea precomputed) -> fp32 ----------------
__global__ __launch_bounds__(256) void k_gxf1(const unsigned short* __restrict__ hprev,
                                              const float* __restrict__ ea,
                                              const int* __restrict__ degi,
                                              const int* __restrict__ offsets,
                                              const int2* __restrict__ pe,
                                              const float* __restrict__ linW,
                                              const float* __restrict__ linb,
                                              const float* __restrict__ edgeW,
                                              const float* __restrict__ edgeb,
                                              float* __restrict__ hnext, int n_nodes, int E) {
    __shared__ float As[4][HDIM];
    __shared__ float es[4][EDIM];
    const int j = threadIdx.x & 63;
    const int q = threadIdx.x >> 6;
    int w  = (blockIdx.x * blockDim.x + threadIdx.x) >> 6;
    const int nw = (gridDim.x * blockDim.x) >> 6;
    for (int n = w; n < n_nodes; n += nw) {
        int rs = offsets[n], re = offsets[n + 1];
        if (rs < 0) rs = 0;
        if (re > E) re = E;
        if (re < rs) re = rs;
        float A0 = 0.f, A1 = 0.f, A2 = 0.f, A3 = 0.f;
        int jj = rs;
        for (; jj + 4 <= re; jj += 4) {
            int s0 = clampidx(pe[jj].x,     n_nodes);
            int s1 = clampidx(pe[jj + 1].x, n_nodes);
            int s2 = clampidx(pe[jj + 2].x, n_nodes);
            int s3 = clampidx(pe[jj + 3].x, n_nodes);
            A0 += b2f(hprev[(size_t)s0 * HDIM + j]);
            A1 += b2f(hprev[(size_t)s1 * HDIM + j]);
            A2 += b2f(hprev[(size_t)s2 * HDIM + j]);
            A3 += b2f(hprev[(size_t)s3 * HDIM + j]);
        }
        for (; jj < re; ++jj) A0 += b2f(hprev[(size_t)clampidx(pe[jj].x, n_nodes) * HDIM + j]);
        As[q][j] = (A0 + A1) + (A2 + A3);
        if (j < EDIM) es[q][j] = ea[(size_t)n * 16 + j];
        __builtin_amdgcn_wave_barrier();   // same-wave LDS write->read ordering
        float acc = (linb[j] + edgeb[j]) * (float)degi[n];
#pragma unroll
        for (int k = 0; k < HDIM; ++k) acc = fmaf(As[q][k], linW[k * HDIM + j], acc);
#pragma unroll
        for (int k = 0; k < EDIM; ++k) acc = fmaf(es[q][k], edgeW[k * HDIM + j], acc);
        hnext[(size_t)n * HDIM + j] = fmaxf(acc, 0.f);
    }
}

// ---------------- fused scores + per-graph max: s[n] from B2, chunk max -> atomicMax ----------------
__global__ __launch_bounds__(256) void k_pscore(const float* __restrict__ h,
                                                const int* __restrict__ batch,
                                                const float* __restrict__ W1,
                                                const float* __restrict__ b1,
                                                const float* __restrict__ W2,
                                                const float* __restrict__ b2,
                                                float* __restrict__ s,
                                                unsigned int* __restrict__ gmaxi, int n_nodes) {
    const int gi = blockIdx.x >> 3;
    const int c  = blockIdx.x & 7;
    __shared__ int se[2];
    __shared__ float hs[4][HDIM];
    __shared__ float redm[4];
    if (threadIdx.x == 0) {
        int lo = 0, hi = n_nodes;
        while (lo < hi) { int mid = (lo + hi) >> 1; if (batch[mid] < gi) lo = mid + 1; else hi = mid; }
        se[0] = lo;
        lo = 0; hi = n_nodes;
        while (lo < hi) { int mid = (lo + hi) >> 1; if (batch[mid] < gi + 1) lo = mid + 1; else hi = mid; }
        se[1] = lo;
    }
    __syncthreads();
    const int start = se[0], len = se[1] - se[0];
    const int cs = start + (int)(((long long)len * c) >> 3);
    const int ce = start + (int)(((long long)len * (c + 1)) >> 3);
    const int j = threadIdx.x & 63;
    const int q = threadIdx.x >> 6;
    const float b2v = b2[0];
    float mx = -3.4e38f;
    for (int i = cs + q; i < ce; i += 4) {
        hs[q][j] = h[(size_t)i * HDIM + j];
        __builtin_amdgcn_wave_barrier();
        float t = 0.f;
        if (j < 32) {
            float z = b1[j];
#pragma unroll
            for (int k = 0; k < HDIM; ++k) z = fmaf(hs[q][k], W1[k * 32 + j], z);
            t = fmaxf(z, 0.f) * W2[j];
        }
        t += __shfl_xor(t, 1, 64);
        t += __shfl_xor(t, 2, 64);
        t += __shfl_xor(t, 4, 64);
        t += __shfl_xor(t, 8, 64);
        t += __shfl_xor(t, 16, 64);
        if (j == 0) {
            float sv = t + b2v;
            s[i] = sv;
            mx = fmaxf(mx, sv);
        }
        __builtin_amdgcn_wave_barrier();   // reads done before next overwrite of hs[q]
    }
    if (j == 0) redm[q] = mx;
    __syncthreads();
    if (threadIdx.x == 0 && ce > cs) {
        float m = fmaxf(fmaxf(redm[0], redm[1]), fmaxf(redm[2], redm[3]));
        atomicMax(&gmaxi[gi], fkey(m));
    }
}

// ---------------- pooling phase B: denom + weighted h sum (fp32 expf once/node) ----------------
__global__ __launch_bounds__(256) void k_poolB(const float* __restrict__ s,
                                               const float* __restrict__ h,
                                               const int* __restrict__ batch,
                                               const unsigned int* __restrict__ gmaxi,
                                               float* __restrict__ gden,
                                               float* __restrict__ gacc, int n_nodes) {
    const int gi = blockIdx.x >> 3;
    const int c  = blockIdx.x & 7;
    __shared__ int se[2];
    __shared__ float ws[256];
    __shared__ float redd[256];
    if (threadIdx.x == 0) {
        int lo = 0, hi = n_nodes;
        while (lo < hi) { int mid = (lo + hi) >> 1; if (batch[mid] < gi) lo = mid + 1; else hi = mid; }
        se[0] = lo;
        lo = 0; hi = n_nodes;
        while (lo < hi) { int mid = (lo + hi) >> 1; if (batch[mid] < gi + 1) lo = mid + 1; else hi = mid; }
        se[1] = lo;
    }
    __syncthreads();
    const int start = se[0], len = se[1] - se[0];
    const int cs = start + (int)(((long long)len * c) >> 3);
    const int ce = start + (int)(((long long)len * (c + 1)) >> 3);
    const float m = funkey(gmaxi[gi]);
    const int tid = threadIdx.x, d = tid & 63, q = tid >> 6;
    float den = 0.f, acc = 0.f;
    for (int t0 = cs; t0 < ce; t0 += 256) {
        const int cnt = (ce - t0 < 256) ? (ce - t0) : 256;
        __syncthreads();                   // ws reuse guard
        if (tid < cnt) {
            float wv = __expf(s[t0 + tid] - m);
            ws[tid] = wv;
            den += wv;
        }
        __syncthreads();
        for (int i = q; i < cnt; i += 4)
            acc = fmaf(h[(size_t)(t0 + i) * HDIM + d], ws[i], acc);
    }
    redd[tid] = den;
    __syncthreads();
    for (int off = 128; off >= 1; off >>= 1) {
        if (tid < off) redd[tid] += redd[tid + off];
        __syncthreads();
    }
    if (tid == 0 && redd[0] != 0.f) atomicAdd(&gden[gi], redd[0]);
    if (acc != 0.f) atomicAdd(&gacc[gi * HDIM + d], acc);
}

// ---------------- decoder: out = relu((gacc/gden)@W1+b1)@W2 + b2; block = 1 graph ----------------
__global__ __launch_bounds__(64) void k_dec_b(const float* __restrict__ gacc,
                                              const float* __restrict__ gden,
                                              const float* __restrict__ W1,
                                              const float* __restrict__ b1,
                                              const float* __restrict__ W2,
                                              const float* __restrict__ b2,
                                              float* __restrict__ out) {
    __shared__ float gg[HDIM];
    __shared__ float zs[32];
    const int gi = blockIdx.x;
    const int j = threadIdx.x;
    const float den = gden[gi];
    gg[j] = (den > 0.f) ? gacc[gi * HDIM + j] / den : 0.f;
    __syncthreads();
    if (j < 32) {
        float z = b1[j];
#pragma unroll
        for (int k = 0; k < HDIM; ++k) z = fmaf(gg[k], W1[k * 32 + j], z);
        zs[j] = fmaxf(z, 0.f);
    }
    __syncthreads();
    if (j < DOUT) {
        float o = b2[j];
#pragma unroll
        for (int i = 0; i < 32; ++i) o = fmaf(zs[i], W2[i * DOUT + j], o);
        out[gi * DOUT + j] = o;
    }
}

extern "C" void kernel_launch(void* const* d_in, const int* in_sizes, int n_in,
                              void* d_out, int out_size, void* d_ws, size_t ws_size,
                              hipStream_t stream) {
    const float* x     = (const float*)d_in[0];
    const int*   ei    = (const int*)d_in[1];
    const float* eattr = (const float*)d_in[2];
    const int*   batch = (const int*)d_in[3];
    const float* encW  = (const float*)d_in[4];
    const float* encb  = (const float*)d_in[5];
    const float* linW  = (const float*)d_in[6];
    const float* linb  = (const float*)d_in[7];
    const float* edgeW = (const float*)d_in[8];
    const float* edgeb = (const float*)d_in[9];
    const float* attW1 = (const float*)d_in[10];
    const float* attb1 = (const float*)d_in[11];
    const float* attW2 = (const float*)d_in[12];
    const float* attb2 = (const float*)d_in[13];
    const float* decW1 = (const float*)d_in[14];
    const float* decb1 = (const float*)d_in[15];
    const float* decW2 = (const float*)d_in[16];
    const float* decb2 = (const float*)d_in[17];

    const int N = in_sizes[0] / DIN;
    const int E = in_sizes[1] / 2;
    const int nblk = (N + SCAN_BS - 1) / SCAN_BS;

    // union region: eb (bf16 E x 16, live degc->gxf0) then B2 (fp32 N x 64, live gxf1->end)
    size_t union_bytes = (size_t)E * 16 * 2;
    size_t b2_bytes = (size_t)N * HDIM * 4;
    if (b2_bytes > union_bytes) union_bytes = b2_bytes;

    size_t need_bytes = union_bytes
                      + (size_t)N * HDIM * 2 * 2  // hb0, hb1
                      + (size_t)N * 16 * 4        // ea
                      + (size_t)N * 4             // sS
                      + (size_t)NGRAPH * (HDIM + 2) * 4 // gacc, gden, gmaxi
                      + (size_t)E * 8             // pe (int2)
                      + (size_t)N * 4             // degi
                      + (size_t)(N + 2) * 4       // offsets
                      + (size_t)E * 4             // rank
                      + 8192 * 4;                 // bsum, boff
    if (ws_size < need_bytes) {
        return;  // diagnostic signature: output stays all-zero (absmax == max|ref| == 488)
    }

    char* base = (char*)d_ws;
    float* B2 = (float*)base;                        // union region (B2 after gxf0)
    unsigned short* eb = (unsigned short*)base;      // union region (eb until gxf0)
    unsigned short* hb0 = (unsigned short*)(base + union_bytes);
    unsigned short* hb1 = hb0 + (size_t)N * HDIM;
    float* ea = (float*)(hb1 + (size_t)N * HDIM);
    float* sS = ea + (size_t)N * 16;
    float* gacc = sS + N;                      // NGRAPH*HDIM
    float* gden = gacc + NGRAPH * HDIM;        // NGRAPH
    unsigned int* gmaxi = (unsigned int*)(gden + NGRAPH); // NGRAPH
    int2* pe     = (int2*)(gmaxi + NGRAPH);
    int* degi    = (int*)(pe + E);
    int* offsets = degi + N;
    int* rank    = offsets + (N + 2);
    int* bsum    = rank + E;
    int* boff    = bsum + 4096;

    hipMemsetAsync(degi, 0, (size_t)N * sizeof(int), stream);
    hipMemsetAsync(gacc, 0, (size_t)NGRAPH * (HDIM + 2) * sizeof(float), stream);

    k_enc_b<<<(N + 3) / 4, 256, 0, stream>>>(x, encW, encb, hb0, N);

    // degree + rank + eattr bf16 convert (edge order) in one pass
    k_degc<<<4096, 256, 0, stream>>>(ei, eattr, degi, rank, eb, E, N);

    // CSR build
    k_blocksum<<<nblk, SCAN_BS, 0, stream>>>(degi, bsum, N);
    k_bscan<<<1, 64, 0, stream>>>(bsum, boff, offsets, nblk, N, E);
    k_fillofs<<<nblk, 64, 0, stream>>>(degi, boff, offsets, N);
    k_fill<<<(E + 255) / 256, 256, 0, stream>>>(ei, offsets, rank, pe, E, N);

    // layer 0 (random bf16 eattr gather fused): hb1, ea
    k_gxf0<<<2048, 256, 0, stream>>>(hb0, eb, degi, offsets, pe,
                                     linW, linb, edgeW, edgeb, hb1, ea, N, E);

    // layer 1: B2 = relu(gather(hb1) @ W1 + deg*b1 + ea @ We1)   [B2 reuses eb's region]
    k_gxf1<<<2048, 256, 0, stream>>>(hb1, ea, degi, offsets, pe,
                                     linW + HDIM * HDIM, linb + HDIM,
                                     edgeW + EDIM * HDIM, edgeb + HDIM, B2, N, E);

    // fused scores + per-graph max, then weighted pooling
    k_pscore<<<NGRAPH * 8, 256, 0, stream>>>(B2, batch, attW1, attb1, attW2, attb2,
                                             sS, gmaxi, N);
    k_poolB<<<NGRAPH * 8, 256, 0, stream>>>(sS, B2, batch, gmaxi, gden, gacc, N);
    k_dec_b<<<NGRAPH, 64, 0, stream>>>(gacc, gden, decW1, decb1, decW2, decb2, (float*)d_out);
}

// Round 19
// 566.895 us; speedup vs baseline: 1.0491x; 1.0491x over previous
//
#include <hip/hip_runtime.h>

// Sizes (fixed by the reference)
#define DIN 32
#define HDIM 64
#define DOUT 8
#define NGRAPH 64
#define EDIM 15
#define SCAN_BS 512

__device__ __forceinline__ int clampidx(int v, int n) {
    return ((unsigned)v < (unsigned)n) ? v : 0;
}

// bf16 helpers (round-to-nearest-even store, cheap decode)
__device__ __forceinline__ unsigned short f2b(float f) {
    unsigned int u = __float_as_uint(f);
    u = (u + 0x7FFF + ((u >> 16) & 1)) >> 16;
    return (unsigned short)u;
}
__device__ __forceinline__ float b2f(unsigned short b) {
    return __uint_as_float(((unsigned int)b) << 16);
}

// monotonic float<->uint encoding for atomicMax
__device__ __forceinline__ unsigned int fkey(float f) {
    unsigned int b = __float_as_uint(f);
    return (b & 0x80000000u) ? ~b : (b | 0x80000000u);
}
__device__ __forceinline__ float funkey(unsigned int k) {
    unsigned int b = (k & 0x80000000u) ? (k ^ 0x80000000u) : ~k;
    return __uint_as_float(b);
}

// ---------------- encoder: h0 = relu(x @ enc_W + enc_b) -> bf16; block = 4 nodes ----------------
__global__ __launch_bounds__(256) void k_enc_b(const float* __restrict__ x,
                                               const float* __restrict__ W,
                                               const float* __restrict__ b,
                                               unsigned short* __restrict__ h, int n_nodes) {
    __shared__ float xs[4][DIN];
    const int j = threadIdx.x & 63;
    const int q = threadIdx.x >> 6;
    const int n = blockIdx.x * 4 + q;
    const bool ok = (n < n_nodes);
    if (ok && j < DIN) xs[q][j] = x[(size_t)n * DIN + j];
    __syncthreads();
    if (ok) {
        float acc = b[j];
#pragma unroll
        for (int k = 0; k < DIN; ++k) acc = fmaf(xs[q][k], W[k * HDIM + j], acc);
        h[(size_t)n * HDIM + j] = f2b(fmaxf(acc, 0.f));
    }
}

// ---------------- degree count + per-edge rank (atomic return value) ----------------
__global__ __launch_bounds__(256) void k_deg(const int* __restrict__ ei,
                                             int* __restrict__ degi,
                                             int* __restrict__ rank, int E, int n_nodes) {
    int e = blockIdx.x * blockDim.x + threadIdx.x;
    if (e < E) rank[e] = atomicAdd(&degi[clampidx(ei[E + e], n_nodes)], 1);
}

// ---------------- CSR scan stage 1: per-block sum of degrees ----------------
__global__ __launch_bounds__(SCAN_BS) void k_blocksum(const int* __restrict__ degi,
                                                      int* __restrict__ bsum, int n) {
    __shared__ int red[SCAN_BS];
    const int t = threadIdx.x;
    const int i = blockIdx.x * SCAN_BS + t;
    red[t] = (i < n) ? degi[i] : 0;
    __syncthreads();
    for (int off = SCAN_BS / 2; off >= 1; off >>= 1) {
        if (t < off) red[t] += red[t + off];
        __syncthreads();
    }
    if (t == 0) bsum[blockIdx.x] = red[0];
}

// ---------------- CSR scan stage 2: single-thread exclusive scan of block sums ----------------
__global__ __launch_bounds__(64) void k_bscan(const int* __restrict__ bsum,
                                              int* __restrict__ boff,
                                              int* __restrict__ offsets,
                                              int nblk, int n, int E) {
    if (blockIdx.x == 0 && threadIdx.x == 0) {
        int run = 0;
        for (int b = 0; b < nblk; ++b) { boff[b] = run; run += bsum[b]; }
        offsets[n] = E;
    }
}

// ---------------- CSR scan stage 3: per-block single-thread offset emit ----------------
__global__ __launch_bounds__(64) void k_fillofs(const int* __restrict__ degi,
                                                const int* __restrict__ boff,
                                                int* __restrict__ offsets, int n) {
    if (threadIdx.x != 0) return;
    const int b = blockIdx.x;
    int run = boff[b];
    const int i0 = b * SCAN_BS;
    const int i1 = (i0 + SCAN_BS < n) ? i0 + SCAN_BS : n;
    for (int i = i0; i < i1; ++i) {
        offsets[i] = run;
        run += degi[i];
    }
}

// ---------------- CSR fill (atomic-free): pe[offsets[dst]+rank[e]] <- (src, e) ----------------
__global__ __launch_bounds__(256) void k_fill(const int* __restrict__ ei,
                                              const int* __restrict__ offsets,
                                              const int* __restrict__ rank,
                                              int2* __restrict__ pe, int E, int n_nodes) {
    int e = blockIdx.x * blockDim.x + threadIdx.x;
    if (e >= E) return;
    int dst = clampidx(ei[E + e], n_nodes);
    int pos = offsets[dst] + rank[e];
    if ((unsigned)pos < (unsigned)E) pe[pos] = make_int2(clampidx(ei[e], n_nodes), e);
}

// ---------------- layer 0 fused: gather(h bf16) + gather(eattr fp32) + transform -> hb1, ea ----------------
__global__ __launch_bounds__(256) void k_gxf0(const unsigned short* __restrict__ hprev,
                                              const float* __restrict__ eattr,
                                              const int* __restrict__ degi,
                                              const int* __restrict__ offsets,
                                              const int2* __restrict__ pe,
                                              const float* __restrict__ linW,
                                              const float* __restrict__ linb,
                                              const float* __restrict__ edgeW,
                                              const float* __restrict__ edgeb,
                                              unsigned short* __restrict__ hnext,
                                              float* __restrict__ ea_out,
                                              int n_nodes, int E) {
    __shared__ float As[4][HDIM];
    __shared__ float es[4][EDIM];
    const int j = threadIdx.x & 63;
    const int q = threadIdx.x >> 6;
    const bool ed = (j < EDIM);
    int w  = (blockIdx.x * blockDim.x + threadIdx.x) >> 6;
    const int nw = (gridDim.x * blockDim.x) >> 6;
    for (int n = w; n < n_nodes; n += nw) {
        int rs = offsets[n], re = offsets[n + 1];
        if (rs < 0) rs = 0;
        if (re > E) re = E;
        if (re < rs) re = rs;
        float A0 = 0.f, A1 = 0.f, A2 = 0.f, A3 = 0.f;
        float e0 = 0.f, e1 = 0.f, e2 = 0.f, e3 = 0.f;
        int jj = rs;
        for (; jj + 4 <= re; jj += 4) {
            int2 p0 = pe[jj], p1 = pe[jj + 1], p2 = pe[jj + 2], p3 = pe[jj + 3];
            int s0 = clampidx(p0.x, n_nodes), s1 = clampidx(p1.x, n_nodes);
            int s2 = clampidx(p2.x, n_nodes), s3 = clampidx(p3.x, n_nodes);
            A0 += b2f(hprev[(size_t)s0 * HDIM + j]);
            A1 += b2f(hprev[(size_t)s1 * HDIM + j]);
            A2 += b2f(hprev[(size_t)s2 * HDIM + j]);
            A3 += b2f(hprev[(size_t)s3 * HDIM + j]);
            if (ed) {
                e0 += eattr[(size_t)clampidx(p0.y, E) * EDIM + j];
                e1 += eattr[(size_t)clampidx(p1.y, E) * EDIM + j];
                e2 += eattr[(size_t)clampidx(p2.y, E) * EDIM + j];
                e3 += eattr[(size_t)clampidx(p3.y, E) * EDIM + j];
            }
        }
        for (; jj < re; ++jj) {
            int2 p = pe[jj];
            A0 += b2f(hprev[(size_t)clampidx(p.x, n_nodes) * HDIM + j]);
            if (ed) e0 += eattr[(size_t)clampidx(p.y, E) * EDIM + j];
        }
        As[q][j] = (A0 + A1) + (A2 + A3);
        float eacc = (e0 + e1) + (e2 + e3);
        if (ed) {
            es[q][j] = eacc;
            ea_out[(size_t)n * 16 + j] = eacc;
        }
        __builtin_amdgcn_wave_barrier();   // same-wave LDS write->read ordering
        float acc = (linb[j] + edgeb[j]) * (float)degi[n];
#pragma unroll
        for (int k = 0; k < HDIM; ++k) acc = fmaf(As[q][k], linW[k * HDIM + j], acc);
#pragma unroll
        for (int k = 0; k < EDIM; ++k) acc = fmaf(es[q][k], edgeW[k * HDIM + j], acc);
        hnext[(size_t)n * HDIM + j] = f2b(fmaxf(acc, 0.f));
    }
}

// ---------------- layer 1: gather(h bf16) + transform (ea precomputed) -> fp32 ----------------
__global__ __launch_bounds__(256) void k_gxf1(const unsigned short* __restrict__ hprev,
                                              const float* __restrict__ ea,
                                              const int* __restrict__ degi,
                                              const int* __restrict__ offsets,
                                              const int2* __restrict__ pe,
                                              const float* __restrict__ linW,
                                              const float* __restrict__ linb,
                                              const float* __restrict__ edgeW,
                                              const float* __restrict__ edgeb,
                                              float* __restrict__ hnext, int n_nodes, int E) {
    __shared__ float As[4][HDIM];
    __shared__ float es[4][EDIM];
    const int j = threadIdx.x & 63;
    const int q = threadIdx.x >> 6;
    int w  = (blockIdx.x * blockDim.x + threadIdx.x) >> 6;
    const int nw = (gridDim.x * blockDim.x) >> 6;
    for (int n = w; n < n_nodes; n += nw) {
        int rs = offsets[n], re = offsets[n + 1];
        if (rs < 0) rs = 0;
        if (re > E) re = E;
        if (re < rs) re = rs;
        float A0 = 0.f, A1 = 0.f, A2 = 0.f, A3 = 0.f;
        int jj = rs;
        for (; jj + 4 <= re; jj += 4) {
            int s0 = clampidx(pe[jj].x,     n_nodes);
            int s1 = clampidx(pe[jj + 1].x, n_nodes);
            int s2 = clampidx(pe[jj + 2].x, n_nodes);
            int s3 = clampidx(pe[jj + 3].x, n_nodes);
            A0 += b2f(hprev[(size_t)s0 * HDIM + j]);
            A1 += b2f(hprev[(size_t)s1 * HDIM + j]);
            A2 += b2f(hprev[(size_t)s2 * HDIM + j]);
            A3 += b2f(hprev[(size_t)s3 * HDIM + j]);
        }
        for (; jj < re; ++jj) A0 += b2f(hprev[(size_t)clampidx(pe[jj].x, n_nodes) * HDIM + j]);
        As[q][j] = (A0 + A1) + (A2 + A3);
        if (j < EDIM) es[q][j] = ea[(size_t)n * 16 + j];
        __builtin_amdgcn_wave_barrier();   // same-wave LDS write->read ordering
        float acc = (linb[j] + edgeb[j]) * (float)degi[n];
#pragma unroll
        for (int k = 0; k < HDIM; ++k) acc = fmaf(As[q][k], linW[k * HDIM + j], acc);
#pragma unroll
        for (int k = 0; k < EDIM; ++k) acc = fmaf(es[q][k], edgeW[k * HDIM + j], acc);
        hnext[(size_t)n * HDIM + j] = fmaxf(acc, 0.f);
    }
}

// ---------------- scores: s = relu(h@W1+b1)@W2 + b2; fp32, block = 4 nodes ----------------
__global__ __launch_bounds__(256) void k_sc_b(const float* __restrict__ h,
                                              const float* __restrict__ W1,
                                              const float* __restrict__ b1,
                                              const float* __restrict__ W2,
                                              const float* __restrict__ b2,
                                              float* __restrict__ s, int n_nodes) {
    __shared__ float hs[4][HDIM];
    const int j = threadIdx.x & 63;
    const int q = threadIdx.x >> 6;
    const int n = blockIdx.x * 4 + q;
    const bool ok = (n < n_nodes);
    if (ok) hs[q][j] = h[(size_t)n * HDIM + j];
    __builtin_amdgcn_wave_barrier();   // one wave per node slice
    float t = 0.f;
    if (ok && j < 32) {
        float z = b1[j];
#pragma unroll
        for (int k = 0; k < HDIM; ++k) z = fmaf(hs[q][k], W1[k * 32 + j], z);
        t = fmaxf(z, 0.f) * W2[j];
    }
    t += __shfl_xor(t, 1, 64);
    t += __shfl_xor(t, 2, 64);
    t += __shfl_xor(t, 4, 64);
    t += __shfl_xor(t, 8, 64);
    t += __shfl_xor(t, 16, 64);
    if (ok && j == 0) s[n] = t + b2[0];
}

// ---------------- pooling phase A: per-graph max (8 chunks/graph, atomicMax) ----------------
__global__ __launch_bounds__(256) void k_poolA(const float* __restrict__ s,
                                               const int* __restrict__ batch,
                                               unsigned int* __restrict__ gmaxi, int n_nodes) {
    const int gi = blockIdx.x >> 3;
    const int c  = blockIdx.x & 7;
    __shared__ int se[2];
    __shared__ float red[256];
    if (threadIdx.x == 0) {
        int lo = 0, hi = n_nodes;
        while (lo < hi) { int mid = (lo + hi) >> 1; if (batch[mid] < gi) lo = mid + 1; else hi = mid; }
        se[0] = lo;
        lo = 0; hi = n_nodes;
        while (lo < hi) { int mid = (lo + hi) >> 1; if (batch[mid] < gi + 1) lo = mid + 1; else hi = mid; }
        se[1] = lo;
    }
    __syncthreads();
    const int start = se[0], len = se[1] - se[0];
    const int cs = start + (int)(((long long)len * c) >> 3);
    const int ce = start + (int)(((long long)len * (c + 1)) >> 3);
    float mx = -3.4e38f;
    for (int i = cs + threadIdx.x; i < ce; i += 256) mx = fmaxf(mx, s[i]);
    red[threadIdx.x] = mx;
    __syncthreads();
    for (int off = 128; off >= 1; off >>= 1) {
        if (threadIdx.x < off) red[threadIdx.x] = fmaxf(red[threadIdx.x], red[threadIdx.x + off]);
        __syncthreads();
    }
    if (threadIdx.x == 0 && ce > cs) atomicMax(&gmaxi[gi], fkey(red[0]));
}

// ---------------- pooling phase B: denom + weighted h sum (fp32 expf once/node) ----------------
__global__ __launch_bounds__(256) void k_poolB(const float* __restrict__ s,
                                               const float* __restrict__ h,
                                               const int* __restrict__ batch,
                                               const unsigned int* __restrict__ gmaxi,
                                               float* __restrict__ gden,
                                               float* __restrict__ gacc, int n_nodes) {
    const int gi = blockIdx.x >> 3;
    const int c  = blockIdx.x & 7;
    __shared__ int se[2];
    __shared__ float ws[256];
    __shared__ float redd[256];
    if (threadIdx.x == 0) {
        int lo = 0, hi = n_nodes;
        while (lo < hi) { int mid = (lo + hi) >> 1; if (batch[mid] < gi) lo = mid + 1; else hi = mid; }
        se[0] = lo;
        lo = 0; hi = n_nodes;
        while (lo < hi) { int mid = (lo + hi) >> 1; if (batch[mid] < gi + 1) lo = mid + 1; else hi = mid; }
        se[1] = lo;
    }
    __syncthreads();
    const int start = se[0], len = se[1] - se[0];
    const int cs = start + (int)(((long long)len * c) >> 3);
    const int ce = start + (int)(((long long)len * (c + 1)) >> 3);
    const float m = funkey(gmaxi[gi]);
    const int tid = threadIdx.x, d = tid & 63, q = tid >> 6;
    float den = 0.f, acc = 0.f;
    for (int t0 = cs; t0 < ce; t0 += 256) {
        const int cnt = (ce - t0 < 256) ? (ce - t0) : 256;
        __syncthreads();                   // ws reuse guard
        if (tid < cnt) {
            float wv = __expf(s[t0 + tid] - m);
            ws[tid] = wv;
            den += wv;
        }
        __syncthreads();
        for (int i = q; i < cnt; i += 4)
            acc = fmaf(h[(size_t)(t0 + i) * HDIM + d], ws[i], acc);
    }
    redd[tid] = den;
    __syncthreads();
    for (int off = 128; off >= 1; off >>= 1) {
        if (tid < off) redd[tid] += redd[tid + off];
        __syncthreads();
    }
    if (tid == 0 && redd[0] != 0.f) atomicAdd(&gden[gi], redd[0]);
    if (acc != 0.f) atomicAdd(&gacc[gi * HDIM + d], acc);
}

// ---------------- decoder: out = relu((gacc/gden)@W1+b1)@W2 + b2; block = 1 graph ----------------
__global__ __launch_bounds__(64) void k_dec_b(const float* __restrict__ gacc,
                                              const float* __restrict__ gden,
                                              const float* __restrict__ W1,
                                              const float* __restrict__ b1,
                                              const float* __restrict__ W2,
                                              const float* __restrict__ b2,
                                              float* __restrict__ out) {
    __shared__ float gg[HDIM];
    __shared__ float zs[32];
    const int gi = blockIdx.x;
    const int j = threadIdx.x;
    const float den = gden[gi];
    gg[j] = (den > 0.f) ? gacc[gi * HDIM + j] / den : 0.f;
    __syncthreads();
    if (j < 32) {
        float z = b1[j];
#pragma unroll
        for (int k = 0; k < HDIM; ++k) z = fmaf(gg[k], W1[k * 32 + j], z);
        zs[j] = fmaxf(z, 0.f);
    }
    __syncthreads();
    if (j < DOUT) {
        float o = b2[j];
#pragma unroll
        for (int i = 0; i < 32; ++i) o = fmaf(zs[i], W2[i * DOUT + j], o);
        out[gi * DOUT + j] = o;
    }
}

extern "C" void kernel_launch(void* const* d_in, const int* in_sizes, int n_in,
                              void* d_out, int out_size, void* d_ws, size_t ws_size,
                              hipStream_t stream) {
    const float* x     = (const float*)d_in[0];
    const int*   ei    = (const int*)d_in[1];
    const float* eattr = (const float*)d_in[2];
    const int*   batch = (const int*)d_in[3];
    const float* encW  = (const float*)d_in[4];
    const float* encb  = (const float*)d_in[5];
    const float* linW  = (const float*)d_in[6];
    const float* linb  = (const float*)d_in[7];
    const float* edgeW = (const float*)d_in[8];
    const float* edgeb = (const float*)d_in[9];
    const float* attW1 = (const float*)d_in[10];
    const float* attb1 = (const float*)d_in[11];
    const float* attW2 = (const float*)d_in[12];
    const float* attb2 = (const float*)d_in[13];
    const float* decW1 = (const float*)d_in[14];
    const float* decb1 = (const float*)d_in[15];
    const float* decW2 = (const float*)d_in[16];
    const float* decb2 = (const float*)d_in[17];

    const int N = in_sizes[0] / DIN;
    const int E = in_sizes[1] / 2;
    const int nblk = (N + SCAN_BS - 1) / SCAN_BS;

    size_t need_bytes = (size_t)N * HDIM * 4      // B2
                      + (size_t)N * HDIM * 2 * 2  // hb0, hb1
                      + (size_t)N * 16 * 4        // ea
                      + (size_t)N * 4             // sS
                      + (size_t)NGRAPH * (HDIM + 2) * 4 // gacc, gden, gmaxi
                      + (size_t)E * 8             // pe (int2)
                      + (size_t)N * 4             // degi
                      + (size_t)(N + 2) * 4       // offsets
                      + (size_t)E * 4             // rank
                      + 8192 * 4;                 // bsum, boff
    if (ws_size < need_bytes) {
        return;  // diagnostic signature: output stays all-zero (absmax == max|ref| == 488)
    }

    float* B2 = (float*)d_ws;
    unsigned short* hb0 = (unsigned short*)(B2 + (size_t)N * HDIM);
    unsigned short* hb1 = hb0 + (size_t)N * HDIM;
    float* ea = (float*)(hb1 + (size_t)N * HDIM);
    float* sS = ea + (size_t)N * 16;
    float* gacc = sS + N;                      // NGRAPH*HDIM
    float* gden = gacc + NGRAPH * HDIM;        // NGRAPH
    unsigned int* gmaxi = (unsigned int*)(gden + NGRAPH); // NGRAPH
    int2* pe     = (int2*)(gmaxi + NGRAPH);
    int* degi    = (int*)(pe + E);
    int* offsets = degi + N;
    int* rank    = offsets + (N + 2);
    int* bsum    = rank + E;
    int* boff    = bsum + 4096;

    hipMemsetAsync(degi, 0, (size_t)N * sizeof(int), stream);
    hipMemsetAsync(gacc, 0, (size_t)NGRAPH * (HDIM + 2) * sizeof(float), stream);

    k_enc_b<<<(N + 3) / 4, 256, 0, stream>>>(x, encW, encb, hb0, N);
    k_deg<<<(E + 255) / 256, 256, 0, stream>>>(ei, degi, rank, E, N);

    // CSR build
    k_blocksum<<<nblk, SCAN_BS, 0, stream>>>(degi, bsum, N);
    k_bscan<<<1, 64, 0, stream>>>(bsum, boff, offsets, nblk, N, E);
    k_fillofs<<<nblk, 64, 0, stream>>>(degi, boff, offsets, N);
    k_fill<<<(E + 255) / 256, 256, 0, stream>>>(ei, offsets, rank, pe, E, N);

    // layer 0 (fused fp32 edge_attr aggregation): hb1, ea
    k_gxf0<<<2048, 256, 0, stream>>>(hb0, eattr, degi, offsets, pe,
                                     linW, linb, edgeW, edgeb, hb1, ea, N, E);

    // layer 1: B2 = relu(gather(hb1) @ W1 + deg*b1 + ea @ We1)
    k_gxf1<<<2048, 256, 0, stream>>>(hb1, ea, degi, offsets, pe,
                                     linW + HDIM * HDIM, linb + HDIM,
                                     edgeW + EDIM * HDIM, edgeb + HDIM, B2, N, E);

    k_sc_b<<<(N + 3) / 4, 256, 0, stream>>>(B2, attW1, attb1, attW2, attb2, sS, N);
    k_poolA<<<NGRAPH * 8, 256, 0, stream>>>(sS, batch, gmaxi, N);
    k_poolB<<<NGRAPH * 8, 256, 0, stream>>>(sS, B2, batch, gmaxi, gden, gacc, N);
    k_dec_b<<<NGRAPH, 64, 0, stream>>>(gacc, gden, decW1, decb1, decW2, decb2, (float*)d_out);
}